// Round 7
// baseline (150.980 us; speedup 1.0000x reference)
//
#include <hip/hip_runtime.h>
#include <math.h>

#define FS 4096
#define FT 4096
#define BIGF 3.0e38f
#define KEYINF 0xFFFFFFFFu

typedef float v2f __attribute__((ext_vector_type(2)));

__device__ __forceinline__ unsigned umin32(unsigned a, unsigned b) { return a < b ? a : b; }
__device__ __forceinline__ unsigned umax32(unsigned a, unsigned b) { return a < b ? b : a; }

// v_med3_u32: median of 3 — one VOP3 instruction on gfx950
__device__ __forceinline__ unsigned med3u(unsigned a, unsigned b, unsigned c) {
    unsigned d;
    asm("v_med3_u32 %0, %1, %2, %3" : "=v"(d) : "v"(a), "v"(b), "v"(c));
    return d;
}

// v_and_or_b32: (a & m) | o in one VOP3 (m register-resident)
__device__ __forceinline__ unsigned and_or(unsigned a, unsigned m, unsigned o) {
    unsigned d;
    asm("v_and_or_b32 %0, %1, %2, %3" : "=v"(d) : "v"(a), "v"(m), "v"(o));
    return d;
}

// VOP3P packed fp32. 3-addr form for chain heads...
__device__ __forceinline__ v2f pk_add(v2f a, v2f b) {
    v2f d;
    asm("v_pk_add_f32 %0, %1, %2" : "=v"(d) : "v"(a), "v"(b));
    return d;
}
__device__ __forceinline__ v2f pk_fma(v2f a, v2f b, v2f c) {
    v2f d;
    asm("v_pk_fma_f32 %0, %1, %2, %3" : "=v"(d) : "v"(a), "v"(b), "v"(c));
    return d;
}
// ...tied accumulator form for the rest of the chain (no copy-movs)
__device__ __forceinline__ void pk_fma_acc(v2f& d, v2f a, v2f b) {
    asm("v_pk_fma_f32 %0, %1, %2, %0" : "+v"(d) : "v"(a), "v"(b));
}

// ---------- block reduction helper (all threads must call) ----------
__device__ __forceinline__ float block_reduce_sum(float v) {
    __shared__ float s[8];
    for (int o = 32; o > 0; o >>= 1) v += __shfl_down(v, o, 64);
    int lane = threadIdx.x & 63, wid = threadIdx.x >> 6;
    if (lane == 0) s[wid] = v;
    __syncthreads();
    int nw = blockDim.x >> 6;
    v = (threadIdx.x < (unsigned)nw) ? s[threadIdx.x] : 0.f;
    if (wid == 0)
        for (int o = 4; o > 0; o >>= 1) v += __shfl_down(v, o, 64);
    return v;  // valid in thread 0
}

// compare-exchange on packed keys
#define CE(x, y) { unsigned _n = umin32(x, y); y = umax32(x, y); x = _n; }

// bitonic merge across 32-lane seg groups of sorted-6 lists (INF-pad to 8);
// all lanes end with the merged top-6.
__device__ __forceinline__ void merge32(unsigned s[6]) {
    #pragma unroll
    for (int m = 1; m <= 16; m <<= 1) {
        unsigned b0 = __shfl_xor(s[0], m, 64), b1 = __shfl_xor(s[1], m, 64);
        unsigned b2 = __shfl_xor(s[2], m, 64), b3 = __shfl_xor(s[3], m, 64);
        unsigned b4 = __shfl_xor(s[4], m, 64), b5 = __shfl_xor(s[5], m, 64);
        unsigned l0 = s[0], l1 = s[1];
        unsigned l2 = umin32(s[2], b5), l3 = umin32(s[3], b4);
        unsigned l4 = umin32(s[4], b3), l5 = umin32(s[5], b2);
        unsigned l6 = b1, l7 = b0;
        CE(l0, l4) CE(l1, l5) CE(l2, l6) CE(l3, l7)
        CE(l0, l2) CE(l1, l3) CE(l4, l6) CE(l5, l7)
        CE(l0, l1) CE(l2, l3) CE(l4, l5) CE(l6, l7)
        s[0] = l0; s[1] = l1; s[2] = l2; s[3] = l3; s[4] = l4; s[5] = l5;
    }
}

// ---------- precompute barycenters; zero the output accumulator ----------
// Candidate arrays sbc2/tbc2 use a PAIRED PLANE layout for packed-fp32 reads:
// per 1024-candidate super-tile, pair p of group g couples candidates
// (a, b=a+32), a = tile*1024 + g*64 + p  (g in [0,16), p in [0,32)).
//   plane0 float4[tile*1024 + g*32 + p]       = (xa, xb, ya, yb)
//   plane1 float4[tile*1024 + 512 + g*32 + p] = (za, zb, wa, wb)
// where (x,y,z,w) is the candidate form (-2x,-2y,-2z,|c|^2):
//   dist = p2 + dot3(p, c.xyz) + c.w
// sbcr: raw source barycenter with .w = |bc|^2 (forward query points)
__global__ __launch_bounds__(64) void k_prep(
        const float* __restrict__ sv, const int* __restrict__ sf,
        const float* __restrict__ tv, const int* __restrict__ tf,
        float4* __restrict__ sbc2, float4* __restrict__ tbc2,
        float4* __restrict__ sbcr, float* __restrict__ out) {
    int i = blockIdx.x * 64 + threadIdx.x;
    if (i == 0) out[0] = 0.f;
    if (i >= FS) return;
    const float third = 1.f / 3.f;
    int a = sf[3*i], b = sf[3*i+1], c = sf[3*i+2];
    float x = (sv[3*a  ] + sv[3*b  ] + sv[3*c  ]) * third;
    float y = (sv[3*a+1] + sv[3*b+1] + sv[3*c+1]) * third;
    float z = (sv[3*a+2] + sv[3*b+2] + sv[3*c+2]) * third;
    float n2 = x*x + y*y + z*z;
    sbcr[i] = make_float4(x, y, z, n2);
    int ta = tf[i], tb = tf[FT + i], tc = tf[2*FT + i];
    float tx = (tv[3*ta  ] + tv[3*tb  ] + tv[3*tc  ]) * third;
    float ty = (tv[3*ta+1] + tv[3*tb+1] + tv[3*tc+1]) * third;
    float tz = (tv[3*ta+2] + tv[3*tb+2] + tv[3*tc+2]) * third;
    float tn2 = tx*tx + ty*ty + tz*tz;

    // paired-plane scatter
    int tt = i >> 10, cc = i & 1023;
    int g = cc >> 6, half = (cc >> 5) & 1, pp = cc & 31;
    int lo4 = tt*1024 + g*32 + pp, hi4 = lo4 + 512;
    float* S = (float*)sbc2;
    S[4*lo4 + half]     = -2.f*x;  S[4*lo4 + 2 + half] = -2.f*y;
    S[4*hi4 + half]     = -2.f*z;  S[4*hi4 + 2 + half] = n2;
    float* T = (float*)tbc2;
    T[4*lo4 + half]     = -2.f*tx; T[4*lo4 + 2 + half] = -2.f*ty;
    T[4*hi4 + half]     = -2.f*tz; T[4*hi4 + 2 + half] = tn2;
}

// ---------- fused main kernel: 1152 blocks x 256 threads, NO LDS TILES ----------
// The candidate arrays are 128 KB total — fully L2-resident (FETCH_SIZE ~1 MB
// proves HBM never sees them). r2-r6 showed the LDS pipeline (gl_lds +
// ds_read + 32 barriers/block) costs ~15 us staging + ~23 us ds_read,
// SERIALIZED by the per-phase barriers, regardless of buffering scheme.
// So: read candidates directly from global (L1/L2-served). Lanes 0-31 read
// 32 consecutive float4s (512 B, perfectly coalesced); lanes 32-63 read the
// same lines (broadcast). Zero barriers in the main loop -> loads from
// different waves overlap VALU freely via vmcnt scheduling + TLP.
// Per-lane candidate subsets, visit order, and FP association order are
// bit-identical to r2-r6 (pair (c, c+32), (tt,g) ascending).
// blocks [0,1024)    : reverse loss — 32 points/block (8 slots x 4 pts)
// blocks [1024,1152) : forward loss — 32 faces/block
__global__ __launch_bounds__(256) void k_main(
        const float* __restrict__ sv, const int* __restrict__ sf,
        const float* __restrict__ fp,
        const float* __restrict__ r1u, const float* __restrict__ r2u,
        const float4* __restrict__ sbc2, const float4* __restrict__ tbc2,
        const float4* __restrict__ sbcr, float* __restrict__ out) {
    int tid  = threadIdx.x;
    int seg  = tid & 31;
    int slot = tid >> 5;
    float contrib = 0.f;

    if (blockIdx.x < 1024) {
        // ================= reverse =================
        int pt0  = blockIdx.x * 32 + slot * 4;   // this thread's 4 points
        int face = pt0 >> 3;                      // all 4 share one face

        int a = sf[3*face], b = sf[3*face+1], c = sf[3*face+2];
        float ax = sv[3*a], ay = sv[3*a+1], az = sv[3*a+2];
        float bx = sv[3*b], by = sv[3*b+1], bz = sv[3*b+2];
        float cx = sv[3*c], cy = sv[3*c+1], cz = sv[3*c+2];
        float4 r14 = ((const float4*)r1u)[pt0 >> 2];
        float4 r24 = ((const float4*)r2u)[pt0 >> 2];
        v2f pxb[4], pyb[4], pzb[4], p2b[4];
        {
            float r1a[4] = {r14.x, r14.y, r14.z, r14.w};
            float r2a[4] = {r24.x, r24.y, r24.z, r24.w};
            #pragma unroll
            for (int i = 0; i < 4; ++i) {
                float r1 = sqrtf(r1a[i]);
                float w1 = 1.f - r1, w2 = r1 * (1.f - r2a[i]), w3 = r1 * r2a[i];
                float px = w1*ax + w2*bx + w3*cx;
                float py = w1*ay + w2*by + w3*cy;
                float pz = w1*az + w2*bz + w3*cz;
                float p2 = px*px + py*py + pz*pz;
                pxb[i] = (v2f){px, px}; pyb[i] = (v2f){py, py};
                pzb[i] = (v2f){pz, pz}; p2b[i] = (v2f){p2, p2};
            }
        }

        // per-lane top-3 per point (min + 2 med3 per eval); merged top-6 later
        unsigned s0[4], s1[4], s2[4];
        #pragma unroll
        for (int i = 0; i < 4; ++i) { s0[i]=KEYINF; s1[i]=KEYINF; s2[i]=KEYINF; }
        v2f vm2[4];
        #pragma unroll
        for (int i = 0; i < 4; ++i) vm2[i] = (v2f){BIGF, BIGF};

        unsigned kMask = 0xFFFFF000u;   // register-resident for v_and_or_b32

        for (int tt = 0; tt < 4; ++tt) {
            const float4* Sb = sbc2 + (tt << 10) + seg;
            const float4* Tb = tbc2 + (tt << 10) + seg;
            unsigned jja = (unsigned)((tt << 10) + seg);
            #pragma unroll 4
            for (int g = 0; g < 16; ++g) {
                float4 slo = Sb[(g << 5)];
                float4 shi = Sb[(g << 5) + 512];
                float4 tlo = Tb[(g << 5)];
                float4 thi = Tb[(g << 5) + 512];
                // ---- src sort-scan: pair (jja, jja+32) ----
                {
                    v2f cx2 = {slo.x, slo.y}, cy2 = {slo.z, slo.w};
                    v2f cz2 = {shi.x, shi.y}, cw2 = {shi.z, shi.w};
                    #pragma unroll
                    for (int i = 0; i < 4; ++i) {
                        // d = |p-c|^2 (unclamped; tiny-neg rounding sorts last)
                        v2f d2 = pk_add(cw2, p2b[i]);
                        pk_fma_acc(d2, pzb[i], cz2);
                        pk_fma_acc(d2, pyb[i], cy2);
                        pk_fma_acc(d2, pxb[i], cx2);
                        unsigned ka = and_or(__float_as_uint(d2.x), kMask, jja);
                        unsigned kb = and_or(__float_as_uint(d2.y), kMask, jja + 32u);
                        unsigned n0 = umin32(s0[i], ka);
                        unsigned n1 = med3u(s0[i], s1[i], ka);
                        unsigned n2 = med3u(s1[i], s2[i], ka);
                        s0[i]=n0; s1[i]=n1; s2[i]=n2;
                        n0 = umin32(s0[i], kb);
                        n1 = med3u(s0[i], s1[i], kb);
                        n2 = med3u(s1[i], s2[i], kb);
                        s0[i]=n0; s1[i]=n1; s2[i]=n2;
                    }
                }
                // ---- tgt min-scan ----
                {
                    v2f cx2 = {tlo.x, tlo.y}, cy2 = {tlo.z, tlo.w};
                    v2f cz2 = {thi.x, thi.y}, cw2 = {thi.z, thi.w};
                    #pragma unroll
                    for (int i = 0; i < 4; ++i) {
                        v2f t = pk_fma(pzb[i], cz2, cw2);
                        pk_fma_acc(t, pyb[i], cy2);
                        pk_fma_acc(t, pxb[i], cx2);
                        vm2[i].x = fminf(vm2[i].x, t.x);
                        vm2[i].y = fminf(vm2[i].y, t.y);
                    }
                }
                jja += 64;
            }
        }

        // ---- merges across the 32-lane seg group ----
        float vm[4];
        #pragma unroll
        for (int i = 0; i < 4; ++i) {
            float v = fminf(vm2[i].x, vm2[i].y);
            v = fminf(v, __shfl_xor(v, 1, 64));
            v = fminf(v, __shfl_xor(v, 2, 64));
            v = fminf(v, __shfl_xor(v, 4, 64));
            v = fminf(v, __shfl_xor(v, 8, 64));
            v = fminf(v, __shfl_xor(v, 16, 64));
            vm[i] = v;
        }

        float pf = fp[face];
        float csum = 0.f;
        #pragma unroll
        for (int i = 0; i < 4; ++i) {
            unsigned srt[6] = {s0[i], s1[i], s2[i], KEYINF, KEYINF, KEYINF};
            merge32(srt);
            if (seg == 0) {
                int   q0 = srt[0] & 0xFFF, q1 = srt[1] & 0xFFF, q2 = srt[2] & 0xFFF;
                int   q3 = srt[3] & 0xFFF, q4 = srt[4] & 0xFFF, q5 = srt[5] & 0xFFF;
                float d0 = __uint_as_float(srt[0] & 0xFFFFF000u);
                float d1 = __uint_as_float(srt[1] & 0xFFFFF000u);
                float d2 = __uint_as_float(srt[2] & 0xFFFFF000u);
                float d3 = __uint_as_float(srt[3] & 0xFFFFF000u);
                float d4 = __uint_as_float(srt[4] & 0xFFFFF000u);
                float d5 = __uint_as_float(srt[5] & 0xFFFFF000u);

                int skip = 5;
                if      (q0 == face) skip = 0;
                else if (q1 == face) skip = 1;
                else if (q2 == face) skip = 2;
                else if (q3 == face) skip = 3;
                else if (q4 == face) skip = 4;

                float s = 0.f;
                if (skip != 0) s += fp[q0] * d0;
                if (skip != 1) s += fp[q1] * d1;
                if (skip != 2) s += fp[q2] * d2;
                if (skip != 3) s += fp[q3] * d3;
                if (skip != 4) s += fp[q4] * d4;
                if (skip != 5) s += fp[q5] * d5;

                float mtd = fmaxf(vm[i] + p2b[i].x, 0.f);
                csum += pf * mtd + (1.f - pf) * (s * 0.2f);
            }
        }
        if (seg == 0) contrib = csum;
    } else {
        // ================= forward =================
        int f0 = (blockIdx.x - 1024) * 32 + slot * 4;   // this thread's 4 faces
        float qw[4];
        v2f qxb[4], qyb[4], qzb[4];
        #pragma unroll
        for (int i = 0; i < 4; ++i) {
            float4 q = sbcr[f0 + i];
            qxb[i] = (v2f){q.x, q.x}; qyb[i] = (v2f){q.y, q.y};
            qzb[i] = (v2f){q.z, q.z}; qw[i] = q.w;
        }
        v2f vf2[4];
        #pragma unroll
        for (int i = 0; i < 4; ++i) vf2[i] = (v2f){BIGF, BIGF};

        for (int tt = 0; tt < 4; ++tt) {
            const float4* Tb = tbc2 + (tt << 10) + seg;
            #pragma unroll 4
            for (int g = 0; g < 16; ++g) {
                float4 tlo = Tb[(g << 5)];
                float4 thi = Tb[(g << 5) + 512];
                v2f cx2 = {tlo.x, tlo.y}, cy2 = {tlo.z, tlo.w};
                v2f cz2 = {thi.x, thi.y}, cw2 = {thi.z, thi.w};
                #pragma unroll
                for (int i = 0; i < 4; ++i) {
                    v2f t = pk_fma(qzb[i], cz2, cw2);
                    pk_fma_acc(t, qyb[i], cy2);
                    pk_fma_acc(t, qxb[i], cx2);
                    vf2[i].x = fminf(vf2[i].x, t.x);
                    vf2[i].y = fminf(vf2[i].y, t.y);
                }
            }
        }
        float vf[4];
        #pragma unroll
        for (int i = 0; i < 4; ++i) {
            float v = fminf(vf2[i].x, vf2[i].y);
            v = fminf(v, __shfl_xor(v, 1, 64));
            v = fminf(v, __shfl_xor(v, 2, 64));
            v = fminf(v, __shfl_xor(v, 4, 64));
            v = fminf(v, __shfl_xor(v, 8, 64));
            v = fminf(v, __shfl_xor(v, 16, 64));
            vf[i] = v;
        }
        if (seg == 0)
            contrib = fp[f0  ] * fmaxf(vf[0] + qw[0], 0.f)
                    + fp[f0+1] * fmaxf(vf[1] + qw[1], 0.f)
                    + fp[f0+2] * fmaxf(vf[2] + qw[2], 0.f)
                    + fp[f0+3] * fmaxf(vf[3] + qw[3], 0.f);
    }

    float tot = block_reduce_sum(contrib);
    if (tid == 0) atomicAdd(out, tot);
}

extern "C" void kernel_launch(void* const* d_in, const int* in_sizes, int n_in,
                              void* d_out, int out_size, void* d_ws, size_t ws_size,
                              hipStream_t stream) {
    const float* sv  = (const float*)d_in[0];   // (1,2048,3)
    const int*   sf  = (const int*)  d_in[1];   // (4096,3)
    const float* tv  = (const float*)d_in[2];   // (1,2048,3)
    const int*   tf  = (const int*)  d_in[3];   // (3,4096)
    const float* fp  = (const float*)d_in[4];   // (4096,)
    const float* r1u = (const float*)d_in[5];   // (4096,8)
    const float* r2u = (const float*)d_in[6];   // (4096,8)
    float* out = (float*)d_out;

    char* ws = (char*)d_ws;
    float4* sbc2 = (float4*)(ws);                 // 64 KB, paired-plane layout
    float4* tbc2 = (float4*)(ws + 65536);         // 64 KB, paired-plane layout
    float4* sbcr = (float4*)(ws + 131072);        // 64 KB

    k_prep<<<64,   64,  0, stream>>>(sv, sf, tv, tf, sbc2, tbc2, sbcr, out);
    k_main<<<1152, 256, 0, stream>>>(sv, sf, fp, r1u, r2u, sbc2, tbc2, sbcr, out);
}

// Round 8
// 134.385 us; speedup vs baseline: 1.1235x; 1.1235x over previous
//
#include <hip/hip_runtime.h>
#include <math.h>

#define FS 4096
#define FT 4096
#define TS 512           // candidates per LDS tile phase (float4 -> 8 KB per tile)
#define NPH 8            // phases (NPH * TS = 4096)
#define BIGF 3.0e38f
#define KEYINF 0xFFFFFFFFu

typedef float v2f __attribute__((ext_vector_type(2)));

__device__ __forceinline__ unsigned umin32(unsigned a, unsigned b) { return a < b ? a : b; }
__device__ __forceinline__ unsigned umax32(unsigned a, unsigned b) { return a < b ? b : a; }

// v_med3_u32: median of 3 — one VOP3 instruction on gfx950
__device__ __forceinline__ unsigned med3u(unsigned a, unsigned b, unsigned c) {
    unsigned d;
    asm("v_med3_u32 %0, %1, %2, %3" : "=v"(d) : "v"(a), "v"(b), "v"(c));
    return d;
}

// v_and_or_b32: (a & m) | o in one VOP3 (m register-resident)
__device__ __forceinline__ unsigned and_or(unsigned a, unsigned m, unsigned o) {
    unsigned d;
    asm("v_and_or_b32 %0, %1, %2, %3" : "=v"(d) : "v"(a), "v"(m), "v"(o));
    return d;
}

// VOP3P packed fp32. 3-addr form for chain heads...
__device__ __forceinline__ v2f pk_add(v2f a, v2f b) {
    v2f d;
    asm("v_pk_add_f32 %0, %1, %2" : "=v"(d) : "v"(a), "v"(b));
    return d;
}
__device__ __forceinline__ v2f pk_fma(v2f a, v2f b, v2f c) {
    v2f d;
    asm("v_pk_fma_f32 %0, %1, %2, %3" : "=v"(d) : "v"(a), "v"(b), "v"(c));
    return d;
}
// ...tied accumulator form for the rest of the chain (no copy-movs)
__device__ __forceinline__ void pk_fma_acc(v2f& d, v2f a, v2f b) {
    asm("v_pk_fma_f32 %0, %1, %2, %0" : "+v"(d) : "v"(a), "v"(b));
}

// async global->LDS, 16 B per lane; dest lane-linear (wave base + lane*16)
__device__ __forceinline__ void gl_lds16(const float4* g, float4* l) {
    __builtin_amdgcn_global_load_lds(
        (__attribute__((address_space(1))) void*)(g),
        (__attribute__((address_space(3))) void*)(l), 16, 0, 0);
}

// ---------- block reduction helper (all threads must call) ----------
__device__ __forceinline__ float block_reduce_sum(float v) {
    __shared__ float s[8];
    for (int o = 32; o > 0; o >>= 1) v += __shfl_down(v, o, 64);
    int lane = threadIdx.x & 63, wid = threadIdx.x >> 6;
    if (lane == 0) s[wid] = v;
    __syncthreads();
    int nw = blockDim.x >> 6;
    v = (threadIdx.x < (unsigned)nw) ? s[threadIdx.x] : 0.f;
    if (wid == 0)
        for (int o = 4; o > 0; o >>= 1) v += __shfl_down(v, o, 64);
    return v;  // valid in thread 0
}

// compare-exchange on packed keys
#define CE(x, y) { unsigned _n = umin32(x, y); y = umax32(x, y); x = _n; }

// bitonic merge across 32-lane seg groups of sorted-6 lists (INF-pad to 8);
// all lanes end with the merged top-6.
__device__ __forceinline__ void merge32(unsigned s[6]) {
    #pragma unroll
    for (int m = 1; m <= 16; m <<= 1) {
        unsigned b0 = __shfl_xor(s[0], m, 64), b1 = __shfl_xor(s[1], m, 64);
        unsigned b2 = __shfl_xor(s[2], m, 64), b3 = __shfl_xor(s[3], m, 64);
        unsigned b4 = __shfl_xor(s[4], m, 64), b5 = __shfl_xor(s[5], m, 64);
        unsigned l0 = s[0], l1 = s[1];
        unsigned l2 = umin32(s[2], b5), l3 = umin32(s[3], b4);
        unsigned l4 = umin32(s[4], b3), l5 = umin32(s[5], b2);
        unsigned l6 = b1, l7 = b0;
        CE(l0, l4) CE(l1, l5) CE(l2, l6) CE(l3, l7)
        CE(l0, l2) CE(l1, l3) CE(l4, l6) CE(l5, l7)
        CE(l0, l1) CE(l2, l3) CE(l4, l5) CE(l6, l7)
        s[0] = l0; s[1] = l1; s[2] = l2; s[3] = l3; s[4] = l4; s[5] = l5;
    }
}

// ---------- precompute barycenters; zero the output accumulator ----------
// Candidate arrays sbc2/tbc2 use a PAIRED PLANE layout for packed-fp32 reads:
// per 1024-candidate super-tile, pair p of group g couples candidates
// (a, b=a+32), a = tile*1024 + g*64 + p  (g in [0,16), p in [0,32)).
//   plane0 float4[tile*1024 + g*32 + p]       = (xa, xb, ya, yb)
//   plane1 float4[tile*1024 + 512 + g*32 + p] = (za, zb, wa, wb)
// where (x,y,z,w) is the candidate form (-2x,-2y,-2z,|c|^2):
//   dist = p2 + dot3(p, c.xyz) + c.w
// sbcr: raw source barycenter with .w = |bc|^2 (forward query points)
__global__ __launch_bounds__(64) void k_prep(
        const float* __restrict__ sv, const int* __restrict__ sf,
        const float* __restrict__ tv, const int* __restrict__ tf,
        float4* __restrict__ sbc2, float4* __restrict__ tbc2,
        float4* __restrict__ sbcr, float* __restrict__ out) {
    int i = blockIdx.x * 64 + threadIdx.x;
    if (i == 0) out[0] = 0.f;
    if (i >= FS) return;
    const float third = 1.f / 3.f;
    int a = sf[3*i], b = sf[3*i+1], c = sf[3*i+2];
    float x = (sv[3*a  ] + sv[3*b  ] + sv[3*c  ]) * third;
    float y = (sv[3*a+1] + sv[3*b+1] + sv[3*c+1]) * third;
    float z = (sv[3*a+2] + sv[3*b+2] + sv[3*c+2]) * third;
    float n2 = x*x + y*y + z*z;
    sbcr[i] = make_float4(x, y, z, n2);
    int ta = tf[i], tb = tf[FT + i], tc = tf[2*FT + i];
    float tx = (tv[3*ta  ] + tv[3*tb  ] + tv[3*tc  ]) * third;
    float ty = (tv[3*ta+1] + tv[3*tb+1] + tv[3*tc+1]) * third;
    float tz = (tv[3*ta+2] + tv[3*tb+2] + tv[3*tc+2]) * third;
    float tn2 = tx*tx + ty*ty + tz*tz;

    // paired-plane scatter
    int tt = i >> 10, cc = i & 1023;
    int g = cc >> 6, half = (cc >> 5) & 1, pp = cc & 31;
    int lo4 = tt*1024 + g*32 + pp, hi4 = lo4 + 512;
    float* S = (float*)sbc2;
    S[4*lo4 + half]     = -2.f*x;  S[4*lo4 + 2 + half] = -2.f*y;
    S[4*hi4 + half]     = -2.f*z;  S[4*hi4 + 2 + half] = n2;
    float* T = (float*)tbc2;
    T[4*lo4 + half]     = -2.f*tx; T[4*lo4 + 2 + half] = -2.f*ty;
    T[4*hi4 + half]     = -2.f*tz; T[4*hi4 + 2 + half] = tn2;
}

// ---------- fused main kernel: 1152 blocks x 128 threads, 8 POINTS/LANE ----------
// r0-r7 ledger: all LDS variants ~57 us; VALU-pipe ~35 us + LDS-read ~23 us,
// serialized because LDS:VALU demand is ~1:1 per CU (4 b128 per 192 VALU-cyc
// group x 4 SIMDs sharing one LDS pipe). FIX: 8 points per lane (one full
// face's sample set per thread) -> each candidate-pair read feeds 8 points:
// per-wave ds_reads HALVE, LDS:VALU -> 1:2, LDS stops co-bottlenecking.
// Evals conserved (VALU unchanged). 128-thr blocks (4 slots x 8 pts = 32
// pts/block), grid 1024 rev + 128 fwd (32 faces each) = 2304 waves = 9/CU.
// Staging: r4's proven TS=512 / 8-phase gl_lds scheme (traffic unchanged).
// Per-lane candidate subsets, visit order, pairing, FP association all
// bit-identical to r0-r7 (seg = tid&31, jja = p*512 + g*64 + seg).
__global__ __launch_bounds__(128) void k_main(
        const float* __restrict__ sv, const int* __restrict__ sf,
        const float* __restrict__ fp,
        const float* __restrict__ r1u, const float* __restrict__ r2u,
        const float4* __restrict__ sbc2, const float4* __restrict__ tbc2,
        const float4* __restrict__ sbcr, float* __restrict__ out) {
    __shared__ float4 tileS[TS];
    __shared__ float4 tileT[TS];
    int tid  = threadIdx.x;
    int seg  = tid & 31;
    int slot = tid >> 5;                  // 0..3
    float contrib = 0.f;

    if (blockIdx.x < 1024) {
        // ================= reverse =================
        int pt0  = blockIdx.x * 32 + slot * 8;   // this thread's 8 points
        int face = pt0 >> 3;                      // all 8 = one face's samples

        int a = sf[3*face], b = sf[3*face+1], c = sf[3*face+2];
        float ax = sv[3*a], ay = sv[3*a+1], az = sv[3*a+2];
        float bx = sv[3*b], by = sv[3*b+1], bz = sv[3*b+2];
        float cx = sv[3*c], cy = sv[3*c+1], cz = sv[3*c+2];
        float4 r14a = ((const float4*)r1u)[pt0 >> 2];
        float4 r14b = ((const float4*)r1u)[(pt0 >> 2) + 1];
        float4 r24a = ((const float4*)r2u)[pt0 >> 2];
        float4 r24b = ((const float4*)r2u)[(pt0 >> 2) + 1];
        v2f pxb[8], pyb[8], pzb[8], p2b[8];
        {
            float r1a[8] = {r14a.x, r14a.y, r14a.z, r14a.w,
                            r14b.x, r14b.y, r14b.z, r14b.w};
            float r2a[8] = {r24a.x, r24a.y, r24a.z, r24a.w,
                            r24b.x, r24b.y, r24b.z, r24b.w};
            #pragma unroll
            for (int i = 0; i < 8; ++i) {
                float r1 = sqrtf(r1a[i]);
                float w1 = 1.f - r1, w2 = r1 * (1.f - r2a[i]), w3 = r1 * r2a[i];
                float px = w1*ax + w2*bx + w3*cx;
                float py = w1*ay + w2*by + w3*cy;
                float pz = w1*az + w2*bz + w3*cz;
                float p2 = px*px + py*py + pz*pz;
                pxb[i] = (v2f){px, px}; pyb[i] = (v2f){py, py};
                pzb[i] = (v2f){pz, pz}; p2b[i] = (v2f){p2, p2};
            }
        }

        // per-lane top-3 per point (min + 2 med3 per eval); merged top-6 later
        unsigned s0[8], s1[8], s2[8];
        #pragma unroll
        for (int i = 0; i < 8; ++i) { s0[i]=KEYINF; s1[i]=KEYINF; s2[i]=KEYINF; }
        v2f vm2[8];
        #pragma unroll
        for (int i = 0; i < 8; ++i) vm2[i] = (v2f){BIGF, BIGF};

        unsigned kMask = 0xFFFFF000u;   // register-resident for v_and_or_b32

        for (int p = 0; p < NPH; ++p) {
            int loB = ((p >> 1) << 10) + ((p & 1) << 8);   // plane0 chunk base
            __syncthreads();                 // everyone done reading prev tile
            gl_lds16(&sbc2[loB + tid],       &tileS[tid]);
            gl_lds16(&sbc2[loB + 128 + tid], &tileS[128 + tid]);
            gl_lds16(&sbc2[loB + 512 + tid], &tileS[256 + tid]);
            gl_lds16(&sbc2[loB + 640 + tid], &tileS[384 + tid]);
            gl_lds16(&tbc2[loB + tid],       &tileT[tid]);
            gl_lds16(&tbc2[loB + 128 + tid], &tileT[128 + tid]);
            gl_lds16(&tbc2[loB + 512 + tid], &tileT[256 + tid]);
            gl_lds16(&tbc2[loB + 640 + tid], &tileT[384 + tid]);
            __syncthreads();                 // vmcnt drained: tile ready
            // ---- src sort-scan: 8 pair-groups, 2 candidates (j, j+32) each ----
            unsigned jja = (unsigned)(p * TS + seg);
            #pragma unroll 2
            for (int g = 0; g < 8; ++g) {
                float4 lo = tileS[(g << 5) + seg];
                float4 hi = tileS[256 + (g << 5) + seg];
                v2f cx2 = {lo.x, lo.y}, cy2 = {lo.z, lo.w};
                v2f cz2 = {hi.x, hi.y}, cw2 = {hi.z, hi.w};
                #pragma unroll
                for (int i = 0; i < 8; ++i) {
                    // d = |p-c|^2 (unclamped; tiny-neg rounding sorts last)
                    v2f d2 = pk_add(cw2, p2b[i]);
                    pk_fma_acc(d2, pzb[i], cz2);
                    pk_fma_acc(d2, pyb[i], cy2);
                    pk_fma_acc(d2, pxb[i], cx2);
                    unsigned ka = and_or(__float_as_uint(d2.x), kMask, jja);
                    unsigned kb = and_or(__float_as_uint(d2.y), kMask, jja + 32u);
                    unsigned n0 = umin32(s0[i], ka);
                    unsigned n1 = med3u(s0[i], s1[i], ka);
                    unsigned n2 = med3u(s1[i], s2[i], ka);
                    s0[i]=n0; s1[i]=n1; s2[i]=n2;
                    n0 = umin32(s0[i], kb);
                    n1 = med3u(s0[i], s1[i], kb);
                    n2 = med3u(s1[i], s2[i], kb);
                    s0[i]=n0; s1[i]=n1; s2[i]=n2;
                }
                jja += 64;
            }
            // ---- tgt min-scan ----
            #pragma unroll 2
            for (int g = 0; g < 8; ++g) {
                float4 lo = tileT[(g << 5) + seg];
                float4 hi = tileT[256 + (g << 5) + seg];
                v2f cx2 = {lo.x, lo.y}, cy2 = {lo.z, lo.w};
                v2f cz2 = {hi.x, hi.y}, cw2 = {hi.z, hi.w};
                #pragma unroll
                for (int i = 0; i < 8; ++i) {
                    v2f t = pk_fma(pzb[i], cz2, cw2);
                    pk_fma_acc(t, pyb[i], cy2);
                    pk_fma_acc(t, pxb[i], cx2);
                    vm2[i].x = fminf(vm2[i].x, t.x);
                    vm2[i].y = fminf(vm2[i].y, t.y);
                }
            }
        }

        // ---- merges across the 32-lane seg group ----
        float vm[8];
        #pragma unroll
        for (int i = 0; i < 8; ++i) {
            float v = fminf(vm2[i].x, vm2[i].y);
            v = fminf(v, __shfl_xor(v, 1, 64));
            v = fminf(v, __shfl_xor(v, 2, 64));
            v = fminf(v, __shfl_xor(v, 4, 64));
            v = fminf(v, __shfl_xor(v, 8, 64));
            v = fminf(v, __shfl_xor(v, 16, 64));
            vm[i] = v;
        }

        float pf = fp[face];
        float csum = 0.f;
        #pragma unroll
        for (int i = 0; i < 8; ++i) {
            unsigned srt[6] = {s0[i], s1[i], s2[i], KEYINF, KEYINF, KEYINF};
            merge32(srt);
            if (seg == 0) {
                int   q0 = srt[0] & 0xFFF, q1 = srt[1] & 0xFFF, q2 = srt[2] & 0xFFF;
                int   q3 = srt[3] & 0xFFF, q4 = srt[4] & 0xFFF, q5 = srt[5] & 0xFFF;
                float d0 = __uint_as_float(srt[0] & 0xFFFFF000u);
                float d1 = __uint_as_float(srt[1] & 0xFFFFF000u);
                float d2 = __uint_as_float(srt[2] & 0xFFFFF000u);
                float d3 = __uint_as_float(srt[3] & 0xFFFFF000u);
                float d4 = __uint_as_float(srt[4] & 0xFFFFF000u);
                float d5 = __uint_as_float(srt[5] & 0xFFFFF000u);

                int skip = 5;
                if      (q0 == face) skip = 0;
                else if (q1 == face) skip = 1;
                else if (q2 == face) skip = 2;
                else if (q3 == face) skip = 3;
                else if (q4 == face) skip = 4;

                float s = 0.f;
                if (skip != 0) s += fp[q0] * d0;
                if (skip != 1) s += fp[q1] * d1;
                if (skip != 2) s += fp[q2] * d2;
                if (skip != 3) s += fp[q3] * d3;
                if (skip != 4) s += fp[q4] * d4;
                if (skip != 5) s += fp[q5] * d5;

                float mtd = fmaxf(vm[i] + p2b[i].x, 0.f);
                csum += pf * mtd + (1.f - pf) * (s * 0.2f);
            }
        }
        if (seg == 0) contrib = csum;
    } else {
        // ================= forward =================
        int f0 = (blockIdx.x - 1024) * 32 + slot * 8;   // this thread's 8 faces
        float qw[8];
        v2f qxb[8], qyb[8], qzb[8];
        #pragma unroll
        for (int i = 0; i < 8; ++i) {
            float4 q = sbcr[f0 + i];
            qxb[i] = (v2f){q.x, q.x}; qyb[i] = (v2f){q.y, q.y};
            qzb[i] = (v2f){q.z, q.z}; qw[i] = q.w;
        }
        v2f vf2[8];
        #pragma unroll
        for (int i = 0; i < 8; ++i) vf2[i] = (v2f){BIGF, BIGF};

        for (int p = 0; p < NPH; ++p) {
            int loB = ((p >> 1) << 10) + ((p & 1) << 8);
            __syncthreads();
            gl_lds16(&tbc2[loB + tid],       &tileT[tid]);
            gl_lds16(&tbc2[loB + 128 + tid], &tileT[128 + tid]);
            gl_lds16(&tbc2[loB + 512 + tid], &tileT[256 + tid]);
            gl_lds16(&tbc2[loB + 640 + tid], &tileT[384 + tid]);
            __syncthreads();
            #pragma unroll 2
            for (int g = 0; g < 8; ++g) {
                float4 lo = tileT[(g << 5) + seg];
                float4 hi = tileT[256 + (g << 5) + seg];
                v2f cx2 = {lo.x, lo.y}, cy2 = {lo.z, lo.w};
                v2f cz2 = {hi.x, hi.y}, cw2 = {hi.z, hi.w};
                #pragma unroll
                for (int i = 0; i < 8; ++i) {
                    v2f t = pk_fma(qzb[i], cz2, cw2);
                    pk_fma_acc(t, qyb[i], cy2);
                    pk_fma_acc(t, qxb[i], cx2);
                    vf2[i].x = fminf(vf2[i].x, t.x);
                    vf2[i].y = fminf(vf2[i].y, t.y);
                }
            }
        }
        float vfv[8];
        #pragma unroll
        for (int i = 0; i < 8; ++i) {
            float v = fminf(vf2[i].x, vf2[i].y);
            v = fminf(v, __shfl_xor(v, 1, 64));
            v = fminf(v, __shfl_xor(v, 2, 64));
            v = fminf(v, __shfl_xor(v, 4, 64));
            v = fminf(v, __shfl_xor(v, 8, 64));
            v = fminf(v, __shfl_xor(v, 16, 64));
            vfv[i] = v;
        }
        if (seg == 0) {
            float cs = 0.f;
            #pragma unroll
            for (int i = 0; i < 8; ++i)
                cs += fp[f0 + i] * fmaxf(vfv[i] + qw[i], 0.f);
            contrib = cs;
        }
    }

    float tot = block_reduce_sum(contrib);
    if (tid == 0) atomicAdd(out, tot);
}

extern "C" void kernel_launch(void* const* d_in, const int* in_sizes, int n_in,
                              void* d_out, int out_size, void* d_ws, size_t ws_size,
                              hipStream_t stream) {
    const float* sv  = (const float*)d_in[0];   // (1,2048,3)
    const int*   sf  = (const int*)  d_in[1];   // (4096,3)
    const float* tv  = (const float*)d_in[2];   // (1,2048,3)
    const int*   tf  = (const int*)  d_in[3];   // (3,4096)
    const float* fp  = (const float*)d_in[4];   // (4096,)
    const float* r1u = (const float*)d_in[5];   // (4096,8)
    const float* r2u = (const float*)d_in[6];   // (4096,8)
    float* out = (float*)d_out;

    char* ws = (char*)d_ws;
    float4* sbc2 = (float4*)(ws);                 // 64 KB, paired-plane layout
    float4* tbc2 = (float4*)(ws + 65536);         // 64 KB, paired-plane layout
    float4* sbcr = (float4*)(ws + 131072);        // 64 KB

    k_prep<<<64,   64,  0, stream>>>(sv, sf, tv, tf, sbc2, tbc2, sbcr, out);
    k_main<<<1152, 128, 0, stream>>>(sv, sf, fp, r1u, r2u, sbc2, tbc2, sbcr, out);
}

// Round 9
// 116.696 us; speedup vs baseline: 1.2938x; 1.1516x over previous
//
#include <hip/hip_runtime.h>
#include <math.h>

#define FS 4096
#define FT 4096
#define TS 512           // candidates per LDS tile phase (float4 -> 8 KB per tile)
#define NPH 4            // phases per half (NPH * TS = 2048 = half the candidates)
#define NPT 32768        // total reverse sample points
#define BIGF 3.0e38f
#define KEYINF 0xFFFFFFFFu

typedef float v2f __attribute__((ext_vector_type(2)));

__device__ __forceinline__ unsigned umin32(unsigned a, unsigned b) { return a < b ? a : b; }
__device__ __forceinline__ unsigned umax32(unsigned a, unsigned b) { return a < b ? b : a; }

// v_med3_u32: median of 3 — one VOP3 instruction on gfx950
__device__ __forceinline__ unsigned med3u(unsigned a, unsigned b, unsigned c) {
    unsigned d;
    asm("v_med3_u32 %0, %1, %2, %3" : "=v"(d) : "v"(a), "v"(b), "v"(c));
    return d;
}

// v_and_or_b32: (a & m) | o in one VOP3 (m register-resident)
__device__ __forceinline__ unsigned and_or(unsigned a, unsigned m, unsigned o) {
    unsigned d;
    asm("v_and_or_b32 %0, %1, %2, %3" : "=v"(d) : "v"(a), "v"(m), "v"(o));
    return d;
}

// VOP3P packed fp32. 3-addr form for chain heads...
__device__ __forceinline__ v2f pk_add(v2f a, v2f b) {
    v2f d;
    asm("v_pk_add_f32 %0, %1, %2" : "=v"(d) : "v"(a), "v"(b));
    return d;
}
__device__ __forceinline__ v2f pk_fma(v2f a, v2f b, v2f c) {
    v2f d;
    asm("v_pk_fma_f32 %0, %1, %2, %3" : "=v"(d) : "v"(a), "v"(b), "v"(c));
    return d;
}
// ...tied accumulator form for the rest of the chain (no copy-movs)
__device__ __forceinline__ void pk_fma_acc(v2f& d, v2f a, v2f b) {
    asm("v_pk_fma_f32 %0, %1, %2, %0" : "+v"(d) : "v"(a), "v"(b));
}

// async global->LDS, 16 B per lane; dest lane-linear (wave base + lane*16)
__device__ __forceinline__ void gl_lds16(const float4* g, float4* l) {
    __builtin_amdgcn_global_load_lds(
        (__attribute__((address_space(1))) void*)(g),
        (__attribute__((address_space(3))) void*)(l), 16, 0, 0);
}

// ---------- block reduction helper (all threads must call) ----------
__device__ __forceinline__ float block_reduce_sum(float v) {
    __shared__ float s[8];
    for (int o = 32; o > 0; o >>= 1) v += __shfl_down(v, o, 64);
    int lane = threadIdx.x & 63, wid = threadIdx.x >> 6;
    if (lane == 0) s[wid] = v;
    __syncthreads();
    int nw = blockDim.x >> 6;
    v = (threadIdx.x < (unsigned)nw) ? s[threadIdx.x] : 0.f;
    if (wid == 0)
        for (int o = 4; o > 0; o >>= 1) v += __shfl_down(v, o, 64);
    return v;  // valid in thread 0
}

// compare-exchange on packed keys
#define CE(x, y) { unsigned _n = umin32(x, y); y = umax32(x, y); x = _n; }

// bitonic merge across 32-lane seg groups of sorted-6 lists (INF-pad to 8);
// all lanes end with the merged top-6 (sorted ascending).
__device__ __forceinline__ void merge32(unsigned s[6]) {
    #pragma unroll
    for (int m = 1; m <= 16; m <<= 1) {
        unsigned b0 = __shfl_xor(s[0], m, 64), b1 = __shfl_xor(s[1], m, 64);
        unsigned b2 = __shfl_xor(s[2], m, 64), b3 = __shfl_xor(s[3], m, 64);
        unsigned b4 = __shfl_xor(s[4], m, 64), b5 = __shfl_xor(s[5], m, 64);
        unsigned l0 = s[0], l1 = s[1];
        unsigned l2 = umin32(s[2], b5), l3 = umin32(s[3], b4);
        unsigned l4 = umin32(s[4], b3), l5 = umin32(s[5], b2);
        unsigned l6 = b1, l7 = b0;
        CE(l0, l4) CE(l1, l5) CE(l2, l6) CE(l3, l7)
        CE(l0, l2) CE(l1, l3) CE(l4, l6) CE(l5, l7)
        CE(l0, l1) CE(l2, l3) CE(l4, l5) CE(l6, l7)
        s[0] = l0; s[1] = l1; s[2] = l2; s[3] = l3; s[4] = l4; s[5] = l5;
    }
}

// ---------- precompute barycenters; zero the output accumulator ----------
// Candidate arrays sbc2/tbc2 use a PAIRED PLANE layout for packed-fp32 reads:
// per 1024-candidate super-tile, pair p of group g couples candidates
// (a, b=a+32), a = tile*1024 + g*64 + p  (g in [0,16), p in [0,32)).
//   plane0 float4[tile*1024 + g*32 + p]       = (xa, xb, ya, yb)
//   plane1 float4[tile*1024 + 512 + g*32 + p] = (za, zb, wa, wb)
// where (x,y,z,w) is the candidate form (-2x,-2y,-2z,|c|^2):
//   dist = p2 + dot3(p, c.xyz) + c.w
// sbcr: raw source barycenter with .w = |bc|^2 (forward query points)
__global__ __launch_bounds__(64) void k_prep(
        const float* __restrict__ sv, const int* __restrict__ sf,
        const float* __restrict__ tv, const int* __restrict__ tf,
        float4* __restrict__ sbc2, float4* __restrict__ tbc2,
        float4* __restrict__ sbcr, float* __restrict__ out) {
    int i = blockIdx.x * 64 + threadIdx.x;
    if (i == 0) out[0] = 0.f;
    if (i >= FS) return;
    const float third = 1.f / 3.f;
    int a = sf[3*i], b = sf[3*i+1], c = sf[3*i+2];
    float x = (sv[3*a  ] + sv[3*b  ] + sv[3*c  ]) * third;
    float y = (sv[3*a+1] + sv[3*b+1] + sv[3*c+1]) * third;
    float z = (sv[3*a+2] + sv[3*b+2] + sv[3*c+2]) * third;
    float n2 = x*x + y*y + z*z;
    sbcr[i] = make_float4(x, y, z, n2);
    int ta = tf[i], tb = tf[FT + i], tc = tf[2*FT + i];
    float tx = (tv[3*ta  ] + tv[3*tb  ] + tv[3*tc  ]) * third;
    float ty = (tv[3*ta+1] + tv[3*tb+1] + tv[3*tc+1]) * third;
    float tz = (tv[3*ta+2] + tv[3*tb+2] + tv[3*tc+2]) * third;
    float tn2 = tx*tx + ty*ty + tz*tz;

    // paired-plane scatter
    int tt = i >> 10, cc = i & 1023;
    int g = cc >> 6, half = (cc >> 5) & 1, pp = cc & 31;
    int lo4 = tt*1024 + g*32 + pp, hi4 = lo4 + 512;
    float* S = (float*)sbc2;
    S[4*lo4 + half]     = -2.f*x;  S[4*lo4 + 2 + half] = -2.f*y;
    S[4*hi4 + half]     = -2.f*z;  S[4*hi4 + 2 + half] = n2;
    float* T = (float*)tbc2;
    T[4*lo4 + half]     = -2.f*tx; T[4*lo4 + 2 + half] = -2.f*ty;
    T[4*hi4 + half]     = -2.f*tz; T[4*hi4 + 2 + half] = tn2;
}

// ---------- main kernel: 2304 blocks x 256 threads, CANDIDATE-SPLIT ----------
// r8 decoded OccupancyPercent: measured ~= 0.55 * (grid waves / 8192 slots).
// All prior rounds launched <= 4608 waves (~4.5/SIMD) -> VALU (~30us) and LDS
// (~15us) never overlapped past their ~57us sum. FIX: each rev block scans
// only HALF the candidates (2048) for its 32 points -> 2048 rev + 256 fwd
// blocks = 9216 waves, all 8192 wave slots filled, per-block staging halves
// so TOTAL staging traffic is conserved (r6's regression was 2x traffic).
// Partial per-half results go to workspace; k_merge combines.
// Exactness dominates the old scheme: if per-lane-top-3-over-full-range
// captured the true top-6 (it did: absmax 0), per-lane-top-3-per-half does
// too (strictly weaker collision condition), and merging two half-top-6s
// yields the identical global top-6. Keys/distance chains bit-identical.
// blocks [0,2048)    : rev, half=bid&1, point-group pg=bid>>1 (32 pts)
// blocks [2048,2304) : fwd, half=idx&1, face-group fg=idx>>1 (32 faces)
__global__ __launch_bounds__(256) void k_main(
        const float* __restrict__ sv, const int* __restrict__ sf,
        const float* __restrict__ r1u, const float* __restrict__ r2u,
        const float4* __restrict__ sbc2, const float4* __restrict__ tbc2,
        unsigned* __restrict__ rvk, float* __restrict__ rvm,
        float* __restrict__ pp2v, float* __restrict__ fwdv) {
    __shared__ float4 tileS[TS];
    __shared__ float4 tileT[TS];
    int tid  = threadIdx.x;
    int seg  = tid & 31;
    int slot = tid >> 5;

    if (blockIdx.x < 2048) {
        // ================= reverse (one candidate-half) =================
        int half = blockIdx.x & 1;
        int pg   = blockIdx.x >> 1;
        int pt0  = pg * 32 + slot * 4;            // this thread's 4 points
        int face = pt0 >> 3;                      // all 4 share one face

        int a = sf[3*face], b = sf[3*face+1], c = sf[3*face+2];
        float ax = sv[3*a], ay = sv[3*a+1], az = sv[3*a+2];
        float bx = sv[3*b], by = sv[3*b+1], bz = sv[3*b+2];
        float cx = sv[3*c], cy = sv[3*c+1], cz = sv[3*c+2];
        float4 r14 = ((const float4*)r1u)[pt0 >> 2];
        float4 r24 = ((const float4*)r2u)[pt0 >> 2];
        v2f pxb[4], pyb[4], pzb[4], p2b[4];
        {
            float r1a[4] = {r14.x, r14.y, r14.z, r14.w};
            float r2a[4] = {r24.x, r24.y, r24.z, r24.w};
            #pragma unroll
            for (int i = 0; i < 4; ++i) {
                float r1 = sqrtf(r1a[i]);
                float w1 = 1.f - r1, w2 = r1 * (1.f - r2a[i]), w3 = r1 * r2a[i];
                float px = w1*ax + w2*bx + w3*cx;
                float py = w1*ay + w2*by + w3*cy;
                float pz = w1*az + w2*bz + w3*cz;
                float p2 = px*px + py*py + pz*pz;
                pxb[i] = (v2f){px, px}; pyb[i] = (v2f){py, py};
                pzb[i] = (v2f){pz, pz}; p2b[i] = (v2f){p2, p2};
            }
        }

        unsigned s0[4], s1[4], s2[4];
        #pragma unroll
        for (int i = 0; i < 4; ++i) { s0[i]=KEYINF; s1[i]=KEYINF; s2[i]=KEYINF; }
        v2f vm2[4];
        #pragma unroll
        for (int i = 0; i < 4; ++i) vm2[i] = (v2f){BIGF, BIGF};

        unsigned kMask = 0xFFFFF000u;

        for (int p = 0; p < NPH; ++p) {
            int pp  = half * NPH + p;                       // global phase 0..7
            int loB = ((pp >> 1) << 10) + ((pp & 1) << 8);  // float4 index base
            __syncthreads();
            gl_lds16(&sbc2[loB + tid],       &tileS[tid]);
            gl_lds16(&sbc2[loB + 512 + tid], &tileS[256 + tid]);
            gl_lds16(&tbc2[loB + tid],       &tileT[tid]);
            gl_lds16(&tbc2[loB + 512 + tid], &tileT[256 + tid]);
            __syncthreads();
            // ---- src sort-scan: 8 pair-groups, candidates (j, j+32) ----
            unsigned jja = (unsigned)(pp * TS + seg);
            #pragma unroll 4
            for (int g = 0; g < 8; ++g) {
                float4 lo = tileS[(g << 5) + seg];
                float4 hi = tileS[256 + (g << 5) + seg];
                v2f cx2 = {lo.x, lo.y}, cy2 = {lo.z, lo.w};
                v2f cz2 = {hi.x, hi.y}, cw2 = {hi.z, hi.w};
                #pragma unroll
                for (int i = 0; i < 4; ++i) {
                    v2f d2 = pk_add(cw2, p2b[i]);
                    pk_fma_acc(d2, pzb[i], cz2);
                    pk_fma_acc(d2, pyb[i], cy2);
                    pk_fma_acc(d2, pxb[i], cx2);
                    unsigned ka = and_or(__float_as_uint(d2.x), kMask, jja);
                    unsigned kb = and_or(__float_as_uint(d2.y), kMask, jja + 32u);
                    unsigned n0 = umin32(s0[i], ka);
                    unsigned n1 = med3u(s0[i], s1[i], ka);
                    unsigned n2 = med3u(s1[i], s2[i], ka);
                    s0[i]=n0; s1[i]=n1; s2[i]=n2;
                    n0 = umin32(s0[i], kb);
                    n1 = med3u(s0[i], s1[i], kb);
                    n2 = med3u(s1[i], s2[i], kb);
                    s0[i]=n0; s1[i]=n1; s2[i]=n2;
                }
                jja += 64;
            }
            // ---- tgt min-scan ----
            #pragma unroll 4
            for (int g = 0; g < 8; ++g) {
                float4 lo = tileT[(g << 5) + seg];
                float4 hi = tileT[256 + (g << 5) + seg];
                v2f cx2 = {lo.x, lo.y}, cy2 = {lo.z, lo.w};
                v2f cz2 = {hi.x, hi.y}, cw2 = {hi.z, hi.w};
                #pragma unroll
                for (int i = 0; i < 4; ++i) {
                    v2f t = pk_fma(pzb[i], cz2, cw2);
                    pk_fma_acc(t, pyb[i], cy2);
                    pk_fma_acc(t, pxb[i], cx2);
                    vm2[i].x = fminf(vm2[i].x, t.x);
                    vm2[i].y = fminf(vm2[i].y, t.y);
                }
            }
        }

        // ---- tgt partial minima across the 32-lane seg group ----
        float vm[4];
        #pragma unroll
        for (int i = 0; i < 4; ++i) {
            float v = fminf(vm2[i].x, vm2[i].y);
            v = fminf(v, __shfl_xor(v, 1, 64));
            v = fminf(v, __shfl_xor(v, 2, 64));
            v = fminf(v, __shfl_xor(v, 4, 64));
            v = fminf(v, __shfl_xor(v, 8, 64));
            v = fminf(v, __shfl_xor(v, 16, 64));
            vm[i] = v;
        }

        // ---- per-point: merge half-top-6, write partials ----
        #pragma unroll
        for (int i = 0; i < 4; ++i) {
            unsigned srt[6] = {s0[i], s1[i], s2[i], KEYINF, KEYINF, KEYINF};
            merge32(srt);
            if (seg == 0) {
                int pt = pt0 + i;
                unsigned* kb = rvk + half * 6 * NPT + pt;   // plane layout
                kb[0]       = srt[0];  kb[NPT]   = srt[1];
                kb[2*NPT]   = srt[2];  kb[3*NPT] = srt[3];
                kb[4*NPT]   = srt[4];  kb[5*NPT] = srt[5];
                rvm[half * NPT + pt] = vm[i];
                if (half == 0) pp2v[pt] = p2b[i].x;
            }
        }
    } else {
        // ================= forward (one candidate-half) =================
        int idx  = blockIdx.x - 2048;
        int half = idx & 1;
        int fg   = idx >> 1;                      // 0..127
        int f0   = fg * 32 + slot * 4;            // this thread's 4 faces
        const float4* sbcr = tbc2 + FS;           // see launch: sbcr follows tbc2? no —
        // (sbcr passed via pp2v? keep it simple: fwd only needs tbc2 + store)
        float4 q0, q1, q2, q3;
        {
            // raw barycenters are reconstructible from sbc2: (x,y,z) = -0.5*c.xyz
            // but we stored sbcr separately; fwd reads it via rvk-adjacent param.
            // Simplest: recompute from sf/sv like reverse does is costly; instead
            // read candidate form from paired planes and negate-halve.
            // f0..f0+3 lie in super-tile tt=f0>>10, cc layout per k_prep.
            #pragma unroll
            for (int i = 0; i < 4; ++i) {
                int f = f0 + i;
                int tt = f >> 10, cc = f & 1023;
                int g = cc >> 6, hh = (cc >> 5) & 1, ppn = cc & 31;
                int lo4 = tt*1024 + g*32 + ppn, hi4 = lo4 + 512;
                const float* S = (const float*)sbc2;
                float x = -0.5f * S[4*lo4 + hh];
                float y = -0.5f * S[4*lo4 + 2 + hh];
                float z = -0.5f * S[4*hi4 + hh];
                float w =         S[4*hi4 + 2 + hh];
                float4 q = make_float4(x, y, z, w);
                if (i == 0) q0 = q; else if (i == 1) q1 = q;
                else if (i == 2) q2 = q; else q3 = q;
            }
        }
        float qw[4] = {q0.w, q1.w, q2.w, q3.w};
        v2f qxb[4] = {{q0.x,q0.x},{q1.x,q1.x},{q2.x,q2.x},{q3.x,q3.x}};
        v2f qyb[4] = {{q0.y,q0.y},{q1.y,q1.y},{q2.y,q2.y},{q3.y,q3.y}};
        v2f qzb[4] = {{q0.z,q0.z},{q1.z,q1.z},{q2.z,q2.z},{q3.z,q3.z}};
        v2f vf2[4];
        #pragma unroll
        for (int i = 0; i < 4; ++i) vf2[i] = (v2f){BIGF, BIGF};

        for (int p = 0; p < NPH; ++p) {
            int pp  = half * NPH + p;
            int loB = ((pp >> 1) << 10) + ((pp & 1) << 8);
            __syncthreads();
            gl_lds16(&tbc2[loB + tid],       &tileT[tid]);
            gl_lds16(&tbc2[loB + 512 + tid], &tileT[256 + tid]);
            __syncthreads();
            #pragma unroll 4
            for (int g = 0; g < 8; ++g) {
                float4 lo = tileT[(g << 5) + seg];
                float4 hi = tileT[256 + (g << 5) + seg];
                v2f cx2 = {lo.x, lo.y}, cy2 = {lo.z, lo.w};
                v2f cz2 = {hi.x, hi.y}, cw2 = {hi.z, hi.w};
                #pragma unroll
                for (int i = 0; i < 4; ++i) {
                    v2f t = pk_fma(qzb[i], cz2, cw2);
                    pk_fma_acc(t, qyb[i], cy2);
                    pk_fma_acc(t, qxb[i], cx2);
                    vf2[i].x = fminf(vf2[i].x, t.x);
                    vf2[i].y = fminf(vf2[i].y, t.y);
                }
            }
        }
        #pragma unroll
        for (int i = 0; i < 4; ++i) {
            float v = fminf(vf2[i].x, vf2[i].y);
            v = fminf(v, __shfl_xor(v, 1, 64));
            v = fminf(v, __shfl_xor(v, 2, 64));
            v = fminf(v, __shfl_xor(v, 4, 64));
            v = fminf(v, __shfl_xor(v, 8, 64));
            v = fminf(v, __shfl_xor(v, 16, 64));
            if (seg == 0) fwdv[half * FS + f0 + i] = v;
        }
    }
}

// ---------- merge kernel: combine halves + epilogue ----------
// blocks [0,128)   : 32768 reverse points, 1/thread
// blocks [128,144) : 4096 forward faces, 1/thread
__global__ __launch_bounds__(256) void k_merge(
        const float* __restrict__ fp, const float4* __restrict__ sbcr,
        const unsigned* __restrict__ rvk, const float* __restrict__ rvm,
        const float* __restrict__ pp2v, const float* __restrict__ fwdv,
        float* __restrict__ out) {
    int tid = threadIdx.x;
    float contrib = 0.f;
    if (blockIdx.x < 128) {
        int pt = blockIdx.x * 256 + tid;
        int face = pt >> 3;
        unsigned a0 = rvk[pt],         a1 = rvk[NPT + pt];
        unsigned a2 = rvk[2*NPT + pt], a3 = rvk[3*NPT + pt];
        unsigned a4 = rvk[4*NPT + pt], a5 = rvk[5*NPT + pt];
        unsigned b0 = rvk[6*NPT + pt], b1 = rvk[7*NPT + pt];
        unsigned b2 = rvk[8*NPT + pt], b3 = rvk[9*NPT + pt];
        unsigned b4 = rvk[10*NPT + pt], b5 = rvk[11*NPT + pt];
        // 6 smallest of the 12 (both lists sorted ascending): crossover mins
        a0 = umin32(a0, b5); a1 = umin32(a1, b4); a2 = umin32(a2, b3);
        a3 = umin32(a3, b2); a4 = umin32(a4, b1); a5 = umin32(a5, b0);
        float vm = fminf(rvm[pt], rvm[NPT + pt]);
        float p2 = pp2v[pt];
        float pf = fp[face];
        // exclude self if present, else exclude max (== sorted-6th)
        unsigned mx = umax32(umax32(umax32(a0, a1), umax32(a2, a3)),
                             umax32(a4, a5));
        float ss = 0.f; unsigned ex = mx;
        {
            int q; float d;
            q = a0 & 0xFFF; d = __uint_as_float(a0 & 0xFFFFF000u);
            ss += fp[q] * d; if (q == face) ex = a0;
            q = a1 & 0xFFF; d = __uint_as_float(a1 & 0xFFFFF000u);
            ss += fp[q] * d; if (q == face) ex = a1;
            q = a2 & 0xFFF; d = __uint_as_float(a2 & 0xFFFFF000u);
            ss += fp[q] * d; if (q == face) ex = a2;
            q = a3 & 0xFFF; d = __uint_as_float(a3 & 0xFFFFF000u);
            ss += fp[q] * d; if (q == face) ex = a3;
            q = a4 & 0xFFF; d = __uint_as_float(a4 & 0xFFFFF000u);
            ss += fp[q] * d; if (q == face) ex = a4;
            q = a5 & 0xFFF; d = __uint_as_float(a5 & 0xFFFFF000u);
            ss += fp[q] * d; if (q == face) ex = a5;
        }
        ss -= fp[ex & 0xFFF] * __uint_as_float(ex & 0xFFFFF000u);
        float mtd = fmaxf(vm + p2, 0.f);
        contrib = pf * mtd + (1.f - pf) * (ss * 0.2f);
    } else {
        int f = (blockIdx.x - 128) * 256 + tid;
        float vf = fminf(fwdv[f], fwdv[FS + f]);
        float qw = ((const float*)sbcr)[4*f + 3];
        contrib = fp[f] * fmaxf(vf + qw, 0.f);
    }
    float tot = block_reduce_sum(contrib);
    if (tid == 0) atomicAdd(out, tot);
}

extern "C" void kernel_launch(void* const* d_in, const int* in_sizes, int n_in,
                              void* d_out, int out_size, void* d_ws, size_t ws_size,
                              hipStream_t stream) {
    const float* sv  = (const float*)d_in[0];   // (1,2048,3)
    const int*   sf  = (const int*)  d_in[1];   // (4096,3)
    const float* tv  = (const float*)d_in[2];   // (1,2048,3)
    const int*   tf  = (const int*)  d_in[3];   // (3,4096)
    const float* fp  = (const float*)d_in[4];   // (4096,)
    const float* r1u = (const float*)d_in[5];   // (4096,8)
    const float* r2u = (const float*)d_in[6];   // (4096,8)
    float* out = (float*)d_out;

    char* ws = (char*)d_ws;
    float4*   sbc2 = (float4*)(ws);                    // 64 KB, paired planes
    float4*   tbc2 = (float4*)(ws + 65536);            // 64 KB, paired planes
    float4*   sbcr = (float4*)(ws + 131072);           // 64 KB, raw + |bc|^2
    unsigned* rvk  = (unsigned*)(ws + 196608);         // 12 x 32768 u32 = 1.5 MB
    float*    rvm  = (float*)(ws + 196608 + 1572864);  // 2 x 32768 f32
    float*    pp2v = (float*)(ws + 2031616);           // 32768 f32
    float*    fwdv = (float*)(ws + 2162688);           // 2 x 4096 f32

    k_prep <<<64,   64,  0, stream>>>(sv, sf, tv, tf, sbc2, tbc2, sbcr, out);
    k_main <<<2304, 256, 0, stream>>>(sv, sf, r1u, r2u, sbc2, tbc2,
                                      rvk, rvm, pp2v, fwdv);
    k_merge<<<144,  256, 0, stream>>>(fp, sbcr, rvk, rvm, pp2v, fwdv, out);
}